// Round 1
// baseline (892.251 us; speedup 1.0000x reference)
//
#include <hip/hip_runtime.h>
#include <math.h>

#define L_SEQ 4096
#define DMODEL 512
#define DIN    1024
#define DI     1024
#define DS     16
#define DC     4
#define DTR    32
#define NCHK   64   // number of chunks
#define CL     64   // chunk length (NCHK*CL == L_SEQ)

// ---------------------------------------------------------------------------
// Tiled f32 GEMM: C[m,n] = act(sum_k A[m,k]*W[n,k] + bias[n]) (+ C[m,n] if ADDDEST)
// A: (M x K) row-major with stride lda. W: (N x K) packed. All M,N,K divide tiles.
// BM=BN=64, BK=16, 256 threads, 4x4 per thread.
// ACT: 0=none 1=relu 2=tanh 3=softplus
// ---------------------------------------------------------------------------
template <int ACT, bool BIAS, bool ADDDEST>
__global__ __launch_bounds__(256) void gemm_bt(
    const float* __restrict__ A, int lda,
    const float* __restrict__ W,
    const float* __restrict__ bias,
    float* __restrict__ C, int ldc, int K)
{
    __shared__ float sA[16][68];
    __shared__ float sB[16][68];
    const int tid = threadIdx.x;
    const int tx = tid & 15, ty = tid >> 4;
    const int m0 = blockIdx.y * 64, n0 = blockIdx.x * 64;
    const int lr = tid >> 2;            // 0..63 row within tile
    const int lk = (tid & 3) << 2;      // 0,4,8,12 k offset
    float acc[4][4] = {};
    const float* Ap = A + (size_t)(m0 + lr) * lda + lk;
    const float* Wp = W + (size_t)(n0 + lr) * K + lk;
    for (int k0 = 0; k0 < K; k0 += 16) {
        float4 a4 = *(const float4*)(Ap + k0);
        float4 b4 = *(const float4*)(Wp + k0);
        __syncthreads();
        sA[lk + 0][lr] = a4.x; sA[lk + 1][lr] = a4.y;
        sA[lk + 2][lr] = a4.z; sA[lk + 3][lr] = a4.w;
        sB[lk + 0][lr] = b4.x; sB[lk + 1][lr] = b4.y;
        sB[lk + 2][lr] = b4.z; sB[lk + 3][lr] = b4.w;
        __syncthreads();
#pragma unroll
        for (int kk = 0; kk < 16; ++kk) {
            float4 av = *(const float4*)&sA[kk][ty << 2];
            float4 bv = *(const float4*)&sB[kk][tx << 2];
            float am[4] = {av.x, av.y, av.z, av.w};
            float bm[4] = {bv.x, bv.y, bv.z, bv.w};
#pragma unroll
            for (int i = 0; i < 4; ++i)
#pragma unroll
                for (int j = 0; j < 4; ++j)
                    acc[i][j] = fmaf(am[i], bm[j], acc[i][j]);
        }
    }
#pragma unroll
    for (int i = 0; i < 4; ++i) {
        int m = m0 + (ty << 2) + i;
#pragma unroll
        for (int j = 0; j < 4; ++j) {
            int n = n0 + (tx << 2) + j;
            float v = acc[i][j];
            if (BIAS) v += bias[n];
            if (ACT == 1) v = fmaxf(v, 0.f);
            else if (ACT == 2) v = tanhf(v);
            else if (ACT == 3) v = (v > 20.f) ? v : log1pf(__expf(v));
            if (ADDDEST) v += C[(size_t)m * ldc + n];
            C[(size_t)m * ldc + n] = v;
        }
    }
}

// ---------------------------------------------------------------------------
__global__ void concat_kernel(const float* __restrict__ a,
                              const float* __restrict__ b,
                              float* __restrict__ o)
{
    int i = blockIdx.x * 256 + threadIdx.x;      // over 4096*1024
    int m = i >> 10, k = i & 1023;
    o[i] = (k < 512) ? a[(m << 9) + k] : b[(m << 9) + k - 512];
}

// LayerNorm over D=512. One block (128 threads) per row.
__global__ __launch_bounds__(128) void layernorm_k(
    const float* __restrict__ X, const float* __restrict__ w,
    const float* __restrict__ b, float* __restrict__ Y)
{
    const int r = blockIdx.x, tid = threadIdx.x;
    const size_t base = ((size_t)r << 9) + (tid << 2);
    const float4 v = *(const float4*)&X[base];
    float s = v.x + v.y + v.z + v.w;
#pragma unroll
    for (int o = 32; o; o >>= 1) s += __shfl_down(s, o, 64);
    __shared__ float red[2];
    if ((tid & 63) == 0) red[tid >> 6] = s;
    __syncthreads();
    const float mean = (red[0] + red[1]) * (1.f / 512.f);
    float dx = v.x - mean, dy = v.y - mean, dz = v.z - mean, dw = v.w - mean;
    float q = dx * dx + dy * dy + dz * dz + dw * dw;
#pragma unroll
    for (int o = 32; o; o >>= 1) q += __shfl_down(q, o, 64);
    __shared__ float red2[2];
    if ((tid & 63) == 0) red2[tid >> 6] = q;
    __syncthreads();
    const float rs = rsqrtf((red2[0] + red2[1]) * (1.f / 512.f) + 1e-5f);
    const float4 wv = *(const float4*)&w[tid << 2];
    const float4 bv = *(const float4*)&b[tid << 2];
    float4 ov;
    ov.x = dx * rs * wv.x + bv.x;
    ov.y = dy * rs * wv.y + bv.y;
    ov.z = dz * rs * wv.z + bv.z;
    ov.w = dw * rs * wv.w + bv.w;
    *(float4*)&Y[base] = ov;
}

// depthwise causal conv (DC=4) + SiLU. thread per (t,d).
__global__ void conv_silu_k(const float* __restrict__ X,
                            const float* __restrict__ cw,
                            const float* __restrict__ cb,
                            float* __restrict__ XC)
{
    int i = blockIdx.x * 256 + threadIdx.x;      // 4096*1024
    int d = i & (DI - 1);
    int t = i >> 10;
    float acc = cb[d];
#pragma unroll
    for (int k = 0; k < DC; ++k) {
        int ts = t + k - (DC - 1);
        if (ts >= 0) acc = fmaf(X[((size_t)ts << 10) + d], cw[(d << 2) + k], acc);
    }
    float sg = 1.f / (1.f + __expf(-acc));
    XC[i] = acc * sg;
}

// ---------------------------------------------------------------------------
// Selective scan, chunked. Thread owns one channel d for one chunk (16 states in regs).
// ---------------------------------------------------------------------------
__global__ __launch_bounds__(256) void scanA_k(
    const float* __restrict__ dt, const float* __restrict__ xc,
    const float* __restrict__ xdbl, const float* __restrict__ Alog,
    float* __restrict__ sP, float* __restrict__ sH)
{
    const int d = blockIdx.x * 256 + threadIdx.x;
    const int c = blockIdx.y;
    __shared__ float Bs[CL][DS];
    for (int idx = threadIdx.x; idx < CL * DS; idx += 256) {
        int t = idx / DS, s = idx % DS;
        Bs[t][s] = xdbl[(size_t)(c * CL + t) * 64 + 32 + s];
    }
    __syncthreads();
    float As[DS], h[DS], P[DS];
#pragma unroll
    for (int s = 0; s < DS; ++s) {
        As[s] = -__expf(Alog[d * DS + s]);
        h[s] = 0.f; P[s] = 1.f;
    }
    for (int t = 0; t < CL; ++t) {
        size_t tg = (size_t)(c * CL + t);
        float dtv = dt[(tg << 10) + d];
        float xv  = xc[(tg << 10) + d];
        float dx = dtv * xv;
#pragma unroll
        for (int s = 0; s < DS; ++s) {
            float a = __expf(dtv * As[s]);
            h[s] = fmaf(a, h[s], dx * Bs[t][s]);
            P[s] *= a;
        }
    }
    size_t base = ((size_t)c * DI + d) * DS;
#pragma unroll
    for (int s = 0; s < DS; ++s) { sP[base + s] = P[s]; sH[base + s] = h[s]; }
}

__global__ __launch_bounds__(256) void scanB_k(
    const float* __restrict__ sP, const float* __restrict__ sH,
    float* __restrict__ Hin)
{
    int p = blockIdx.x * 256 + threadIdx.x;     // 16384 (d,s) pairs
    float run = 0.f;
    for (int c = 0; c < NCHK; ++c) {
        size_t idx = (size_t)c * DI * DS + p;
        Hin[idx] = run;
        run = fmaf(sP[idx], run, sH[idx]);
    }
}

__global__ __launch_bounds__(256) void scanC_k(
    const float* __restrict__ dt, const float* __restrict__ xc,
    const float* __restrict__ xdbl, const float* __restrict__ Alog,
    const float* __restrict__ Dp, const float* __restrict__ Z,
    const float* __restrict__ Hin, float* __restrict__ yz)
{
    const int d = blockIdx.x * 256 + threadIdx.x;
    const int c = blockIdx.y;
    __shared__ float Bs[CL][DS], Cs[CL][DS];
    for (int idx = threadIdx.x; idx < CL * DS; idx += 256) {
        int t = idx / DS, s = idx % DS;
        Bs[t][s] = xdbl[(size_t)(c * CL + t) * 64 + 32 + s];
        Cs[t][s] = xdbl[(size_t)(c * CL + t) * 64 + 48 + s];
    }
    __syncthreads();
    float As[DS], h[DS];
    size_t hbase = ((size_t)c * DI + d) * DS;
#pragma unroll
    for (int s = 0; s < DS; ++s) {
        As[s] = -__expf(Alog[d * DS + s]);
        h[s] = Hin[hbase + s];
    }
    const float Dd = Dp[d];
    for (int t = 0; t < CL; ++t) {
        size_t tg = (size_t)(c * CL + t);
        float dtv = dt[(tg << 10) + d];
        float xv  = xc[(tg << 10) + d];
        float dx = dtv * xv;
        float y = 0.f;
#pragma unroll
        for (int s = 0; s < DS; ++s) {
            float a = __expf(dtv * As[s]);
            h[s] = fmaf(a, h[s], dx * Bs[t][s]);
            y = fmaf(h[s], Cs[t][s], y);
        }
        y = fmaf(Dd, xv, y);
        float zv = Z[(tg << 10) + d];
        float sg = 1.f / (1.f + __expf(-zv));
        yz[(tg << 10) + d] = y * (zv * sg);
    }
}

// ---------------------------------------------------------------------------
// Attention pooling tail
// ---------------------------------------------------------------------------
__global__ void score_k(const float* __restrict__ At,
                        const float* __restrict__ w2,
                        const float* __restrict__ b2,
                        float* __restrict__ sc)
{
    int t = blockIdx.x * 256 + threadIdx.x;
    const float4* a = (const float4*)(At + ((size_t)t << 7));
    const float4* w = (const float4*)w2;
    float acc = 0.f;
#pragma unroll
    for (int j = 0; j < 32; ++j) {
        float4 av = a[j], wv = w[j];
        acc += av.x * wv.x + av.y * wv.y + av.z * wv.z + av.w * wv.w;
    }
    sc[t] = acc + b2[0];
}

__global__ __launch_bounds__(256) void softmax_k(const float* __restrict__ s,
                                                 float* __restrict__ p)
{
    const int tid = threadIdx.x;
    float vals[16];
#pragma unroll
    for (int i = 0; i < 4; ++i) {
        float4 v = *(const float4*)&s[(tid << 4) + (i << 2)];
        vals[i * 4 + 0] = v.x; vals[i * 4 + 1] = v.y;
        vals[i * 4 + 2] = v.z; vals[i * 4 + 3] = v.w;
    }
    float mx = -1e30f;
#pragma unroll
    for (int i = 0; i < 16; ++i) mx = fmaxf(mx, vals[i]);
#pragma unroll
    for (int o = 32; o; o >>= 1) mx = fmaxf(mx, __shfl_xor(mx, o, 64));
    __shared__ float red[4];
    if ((tid & 63) == 0) red[tid >> 6] = mx;
    __syncthreads();
    mx = fmaxf(fmaxf(red[0], red[1]), fmaxf(red[2], red[3]));
    float sum = 0.f, e[16];
#pragma unroll
    for (int i = 0; i < 16; ++i) { e[i] = __expf(vals[i] - mx); sum += e[i]; }
#pragma unroll
    for (int o = 32; o; o >>= 1) sum += __shfl_xor(sum, o, 64);
    __syncthreads();
    if ((tid & 63) == 0) red[tid >> 6] = sum;
    __syncthreads();
    sum = red[0] + red[1] + red[2] + red[3];
    float inv = 1.f / sum;
#pragma unroll
    for (int i = 0; i < 4; ++i) {
        float4 ov;
        ov.x = e[i * 4 + 0] * inv; ov.y = e[i * 4 + 1] * inv;
        ov.z = e[i * 4 + 2] * inv; ov.w = e[i * 4 + 3] * inv;
        *(float4*)&p[(tid << 4) + (i << 2)] = ov;
    }
}

__global__ void pool_partial_k(const float* __restrict__ prob,
                               const float* __restrict__ hln,
                               float* __restrict__ part)
{
    int j = blockIdx.x * 256 + threadIdx.x;     // 0..511
    int c = blockIdx.y;                          // 0..31, 128 t each
    float acc = 0.f;
    for (int t = c * 128; t < (c + 1) * 128; ++t)
        acc = fmaf(prob[t], hln[((size_t)t << 9) + j], acc);
    part[c * 512 + j] = acc;
}

__global__ void pool_reduce_k(const float* __restrict__ part,
                              float* __restrict__ hp)
{
    int j = blockIdx.x * 256 + threadIdx.x;
    float acc = 0.f;
    for (int c = 0; c < 32; ++c) acc += part[c * 512 + j];
    hp[j] = acc;
}

__global__ __launch_bounds__(256) void final_head_k(
    const float* __restrict__ hp, const float* __restrict__ cls_w,
    const float* __restrict__ cls_b, const int* __restrict__ label,
    float* __restrict__ out)
{
    const int w = threadIdx.x >> 6, lane = threadIdx.x & 63;
    float acc = 0.f;
    for (int k = lane; k < 512; k += 64) acc += hp[k] * cls_w[w * 512 + k];
#pragma unroll
    for (int o = 32; o; o >>= 1) acc += __shfl_down(acc, o, 64);
    __shared__ float lg[4];
    if (lane == 0) lg[w] = acc + cls_b[w];
    __syncthreads();
    if (threadIdx.x == 0) {
        float lce[4];
        for (int c = 0; c < 4; ++c) {
            float z = lg[c];
            float hz = 1.f / (1.f + expf(-z));
            float pc = fminf(fmaxf(hz, 1e-6f), 1.f - 1e-6f);
            lce[c] = logf(pc) - log1pf(-pc);
        }
        float mx = fmaxf(fmaxf(lce[0], lce[1]), fmaxf(lce[2], lce[3]));
        float se = 0.f;
        for (int c = 0; c < 4; ++c) se += expf(lce[c] - mx);
        for (int c = 0; c < 4; ++c) out[c] = lce[c];
        for (int c = 0; c < 4; ++c) out[4 + c] = expf(lce[c] - mx) / se;
        int lb = label[0];
        out[8] = -(lce[lb] - mx - logf(se));
    }
}

// ---------------------------------------------------------------------------
extern "C" void kernel_launch(void* const* d_in, const int* in_sizes, int n_in,
                              void* d_out, int out_size, void* d_ws, size_t ws_size,
                              hipStream_t stream)
{
    const float* data_s   = (const float*)d_in[0];
    const float* data_l   = (const float*)d_in[1];
    // d_in[2] = coord_s (unused: packed[:, :, :-2] drops it)
    const int*   label    = (const int*)d_in[3];
    const float* fc1_w    = (const float*)d_in[4];
    const float* fc1_b    = (const float*)d_in[5];
    const float* ln_w     = (const float*)d_in[6];
    const float* ln_b     = (const float*)d_in[7];
    const float* in_proj_w= (const float*)d_in[8];
    const float* conv_w   = (const float*)d_in[9];
    const float* conv_b   = (const float*)d_in[10];
    const float* x_proj_w = (const float*)d_in[11];
    const float* dt_proj_w= (const float*)d_in[12];
    const float* dt_proj_b= (const float*)d_in[13];
    const float* A_log    = (const float*)d_in[14];
    const float* D_param  = (const float*)d_in[15];
    const float* out_proj_w=(const float*)d_in[16];
    const float* norm_w   = (const float*)d_in[17];
    const float* norm_b   = (const float*)d_in[18];
    const float* attn_w1  = (const float*)d_in[19];
    const float* attn_b1  = (const float*)d_in[20];
    const float* attn_w2  = (const float*)d_in[21];
    const float* attn_b2  = (const float*)d_in[22];
    const float* cls_w    = (const float*)d_in[23];
    const float* cls_b    = (const float*)d_in[24];
    float* out = (float*)d_out;

    // workspace layout (floats)
    float* ws = (float*)d_ws;
    size_t off = 0;
    float* Acat = ws + off; off += (size_t)L_SEQ * DIN;       // 4M; reused as XC after fc1
    float* h    = ws + off; off += (size_t)L_SEQ * DMODEL;    // 2M
    float* hn   = ws + off; off += (size_t)L_SEQ * DMODEL;    // 2M; reused as hln at end
    float* X    = ws + off; off += (size_t)L_SEQ * DI;        // 4M; reused as YZ
    float* Zb   = ws + off; off += (size_t)L_SEQ * DI;        // 4M
    float* dtb  = ws + off; off += (size_t)L_SEQ * DI;        // 4M
    float* xdbl = ws + off; off += (size_t)L_SEQ * 64;        // 256K
    float* sP   = ws + off; off += (size_t)NCHK * DI * DS;    // 1M
    float* sH   = ws + off; off += (size_t)NCHK * DI * DS;    // 1M
    float* Hin  = ws + off; off += (size_t)NCHK * DI * DS;    // 1M
    float* At   = ws + off; off += (size_t)L_SEQ * 128;       // 512K
    float* sc   = ws + off; off += L_SEQ;
    float* pb   = ws + off; off += L_SEQ;
    float* part = ws + off; off += 32 * 512;
    float* hp   = ws + off; off += 512;
    if (ws_size < off * sizeof(float)) return;   // workspace too small

    float* XC = Acat;   // conv output overlays Acat (same size)
    float* YZ = X;      // gated scan output overlays X

    // h = relu(concat(data_s, data_l) @ fc1_w.T + fc1_b)
    concat_kernel<<<L_SEQ * DIN / 256, 256, 0, stream>>>(data_s, data_l, Acat);
    gemm_bt<1, true, false><<<dim3(DMODEL / 64, L_SEQ / 64), 256, 0, stream>>>(
        Acat, DIN, fc1_w, fc1_b, h, DMODEL, DIN);

    for (int i = 0; i < 2; ++i) {
        const float* inw = in_proj_w + (size_t)i * 2 * DI * DMODEL;
        const float* cwi = conv_w + (size_t)i * DI * DC;
        const float* cbi = conv_b + (size_t)i * DI;
        const float* xpw = x_proj_w + (size_t)i * 64 * DI;
        const float* dtw = dt_proj_w + (size_t)i * DI * DTR;
        const float* dtbv= dt_proj_b + (size_t)i * DI;
        const float* Alg = A_log + (size_t)i * DI * DS;
        const float* Dpi = D_param + (size_t)i * DI;
        const float* owi = out_proj_w + (size_t)i * DMODEL * DI;

        layernorm_k<<<L_SEQ, 128, 0, stream>>>(h, ln_w + i * DMODEL, ln_b + i * DMODEL, hn);
        // xz = hn @ inw.T : x half, z half
        gemm_bt<0, false, false><<<dim3(DI / 64, L_SEQ / 64), 256, 0, stream>>>(
            hn, DMODEL, inw, nullptr, X, DI, DMODEL);
        gemm_bt<0, false, false><<<dim3(DI / 64, L_SEQ / 64), 256, 0, stream>>>(
            hn, DMODEL, inw + (size_t)DI * DMODEL, nullptr, Zb, DI, DMODEL);
        conv_silu_k<<<L_SEQ * DI / 256, 256, 0, stream>>>(X, cwi, cbi, XC);
        // xdbl = XC @ xpw.T (N=64)
        gemm_bt<0, false, false><<<dim3(1, L_SEQ / 64), 256, 0, stream>>>(
            XC, DI, xpw, nullptr, xdbl, 64, DI);
        // dt = softplus(xdbl[:, :32] @ dtw.T + dtb)
        gemm_bt<3, true, false><<<dim3(DI / 64, L_SEQ / 64), 256, 0, stream>>>(
            xdbl, 64, dtw, dtbv, dtb, DI, DTR);
        // selective scan (chunked)
        scanA_k<<<dim3(DI / 256, NCHK), 256, 0, stream>>>(dtb, XC, xdbl, Alg, sP, sH);
        scanB_k<<<DI * DS / 256, 256, 0, stream>>>(sP, sH, Hin);
        scanC_k<<<dim3(DI / 256, NCHK), 256, 0, stream>>>(dtb, XC, xdbl, Alg, Dpi, Zb, Hin, YZ);
        // h += YZ @ owi.T
        gemm_bt<0, false, true><<<dim3(DMODEL / 64, L_SEQ / 64), 256, 0, stream>>>(
            YZ, DI, owi, nullptr, h, DMODEL, DI);
    }

    // final LN, attention pooling, head
    layernorm_k<<<L_SEQ, 128, 0, stream>>>(h, norm_w, norm_b, hn);
    gemm_bt<2, true, false><<<dim3(128 / 64, L_SEQ / 64), 256, 0, stream>>>(
        hn, DMODEL, attn_w1, attn_b1, At, 128, DMODEL);
    score_k<<<L_SEQ / 256, 256, 0, stream>>>(At, attn_w2, attn_b2, sc);
    softmax_k<<<1, 256, 0, stream>>>(sc, pb);
    pool_partial_k<<<dim3(2, 32), 256, 0, stream>>>(pb, hn, part);
    pool_reduce_k<<<2, 256, 0, stream>>>(part, hp);
    final_head_k<<<1, 256, 0, stream>>>(hp, cls_w, cls_b, label, out);
}

// Round 2
// 508.125 us; speedup vs baseline: 1.7560x; 1.7560x over previous
//
#include <hip/hip_runtime.h>
#include <math.h>

#define L_SEQ 4096
#define DMODEL 512
#define DIN    1024
#define DI     1024
#define DS     16
#define DC     4
#define DTR    32
#define NCHK   64
#define CL     64

typedef __bf16 bf16x8 __attribute__((ext_vector_type(8)));
typedef __bf16 bf16x4 __attribute__((ext_vector_type(4)));
typedef float floatx4 __attribute__((ext_vector_type(4)));

__device__ __forceinline__ void gl2lds16(const __bf16* g, __bf16* l) {
    __builtin_amdgcn_global_load_lds(
        (const __attribute__((address_space(1))) void*)g,
        (__attribute__((address_space(3))) void*)l, 16, 0, 0);
}

// ---------------------------------------------------------------------------
// bf16 MFMA GEMM: C[m,n] (f32) = act(sum_k A[m,k]*W[n,k] + bias) (+C if ADDDEST)
// A: M x lda bf16 row-major. W: N x ldw bf16 row-major. BM=128, BK=32, 256 thr.
// BN=128: 4 waves in 2x2, each 64x64 (4x4 frags). BN=64: 4 waves stacked in M,
// each 32x64 (2x4 frags). m97-style: global_load_lds(16B) staging, 2 barriers.
// ---------------------------------------------------------------------------
template <int BN, int ACT, bool BIAS, bool ADDDEST>
__global__ __launch_bounds__(256) void gemm_mfma(
    const __bf16* __restrict__ A, int lda,
    const __bf16* __restrict__ W, int ldw,
    const float* __restrict__ bias,
    float* __restrict__ C, int ldc, int K)
{
    __shared__ __align__(16) __bf16 sA[128 * 32];
    __shared__ __align__(16) __bf16 sB[BN * 32];
    const int tid = threadIdx.x;
    const int wid = tid >> 6, lane = tid & 63;
    const int m0 = blockIdx.y * 128, n0 = blockIdx.x * BN;

    constexpr int MR = (BN == 128) ? 4 : 2;
    constexpr int NR = 4;
    const int wrow = (BN == 128) ? (wid >> 1) * 64 : wid * 32;
    const int wcol = (BN == 128) ? (wid & 1) * 64 : 0;

    // staging addresses: chunk = 1024B = 16 rows of 32 bf16
    const int srowA0 = wid * 32 + (lane >> 2);     // chunks 2w,2w+1
    const int scol   = (lane & 3) * 8;
    const __bf16* aSrc0 = A + (size_t)(m0 + srowA0) * lda + scol;
    const __bf16* aSrc1 = aSrc0 + 16 * (size_t)lda;
    __bf16* aDst0 = &sA[wid * 1024];
    __bf16* aDst1 = &sA[wid * 1024 + 512];

    const __bf16* bSrc0;
    const __bf16* bSrc1 = nullptr;
    __bf16* bDst0;
    __bf16* bDst1 = nullptr;
    if (BN == 128) {
        bSrc0 = W + (size_t)(n0 + wid * 32 + (lane >> 2)) * ldw + scol;
        bSrc1 = bSrc0 + 16 * (size_t)ldw;
        bDst0 = &sB[wid * 1024];
        bDst1 = &sB[wid * 1024 + 512];
    } else {
        bSrc0 = W + (size_t)(n0 + wid * 16 + (lane >> 2)) * ldw + scol;
        bDst0 = &sB[wid * 512];
    }

    floatx4 acc[MR][NR] = {};
    const int fr = lane & 15;            // frag row/col within 16
    const int fk = (lane >> 4) * 8;      // k offset within 32

    for (int k0 = 0; k0 < K; k0 += 32) {
        __syncthreads();
        gl2lds16(aSrc0 + k0, aDst0);
        gl2lds16(aSrc1 + k0, aDst1);
        gl2lds16(bSrc0 + k0, bDst0);
        if (BN == 128) gl2lds16(bSrc1 + k0, bDst1);
        __syncthreads();
        bf16x8 af[MR], bfv[NR];
#pragma unroll
        for (int i = 0; i < MR; ++i)
            af[i] = *(const bf16x8*)&sA[(wrow + i * 16 + fr) * 32 + fk];
#pragma unroll
        for (int j = 0; j < NR; ++j)
            bfv[j] = *(const bf16x8*)&sB[(wcol + j * 16 + fr) * 32 + fk];
#pragma unroll
        for (int i = 0; i < MR; ++i)
#pragma unroll
            for (int j = 0; j < NR; ++j)
                acc[i][j] = __builtin_amdgcn_mfma_f32_16x16x32_bf16(
                    af[i], bfv[j], acc[i][j], 0, 0, 0);
    }

#pragma unroll
    for (int i = 0; i < MR; ++i)
#pragma unroll
        for (int j = 0; j < NR; ++j) {
            const int n = n0 + wcol + j * 16 + fr;
            float bv = 0.f;
            if (BIAS) bv = bias[n];
#pragma unroll
            for (int r = 0; r < 4; ++r) {
                const int m = m0 + wrow + i * 16 + (lane >> 4) * 4 + r;
                float v = acc[i][j][r] + bv;
                if (ACT == 1) v = fmaxf(v, 0.f);
                const size_t idx = (size_t)m * ldc + n;
                if (ADDDEST) v += C[idx];
                C[idx] = v;
            }
        }
}

// ---------------------------------------------------------------------------
// f32 tiled GEMM (kept for small/low-precision-sensitive ops: dt_proj, attn)
// ---------------------------------------------------------------------------
template <int ACT, bool BIAS, bool ADDDEST>
__global__ __launch_bounds__(256) void gemm_bt(
    const float* __restrict__ A, int lda,
    const float* __restrict__ W,
    const float* __restrict__ bias,
    float* __restrict__ C, int ldc, int K)
{
    __shared__ float sA[16][68];
    __shared__ float sB[16][68];
    const int tid = threadIdx.x;
    const int tx = tid & 15, ty = tid >> 4;
    const int m0 = blockIdx.y * 64, n0 = blockIdx.x * 64;
    const int lr = tid >> 2;
    const int lk = (tid & 3) << 2;
    float acc[4][4] = {};
    const float* Ap = A + (size_t)(m0 + lr) * lda + lk;
    const float* Wp = W + (size_t)(n0 + lr) * K + lk;
    for (int k0 = 0; k0 < K; k0 += 16) {
        float4 a4 = *(const float4*)(Ap + k0);
        float4 b4 = *(const float4*)(Wp + k0);
        __syncthreads();
        sA[lk + 0][lr] = a4.x; sA[lk + 1][lr] = a4.y;
        sA[lk + 2][lr] = a4.z; sA[lk + 3][lr] = a4.w;
        sB[lk + 0][lr] = b4.x; sB[lk + 1][lr] = b4.y;
        sB[lk + 2][lr] = b4.z; sB[lk + 3][lr] = b4.w;
        __syncthreads();
#pragma unroll
        for (int kk = 0; kk < 16; ++kk) {
            float4 av = *(const float4*)&sA[kk][ty << 2];
            float4 bv = *(const float4*)&sB[kk][tx << 2];
            float am[4] = {av.x, av.y, av.z, av.w};
            float bm[4] = {bv.x, bv.y, bv.z, bv.w};
#pragma unroll
            for (int i = 0; i < 4; ++i)
#pragma unroll
                for (int j = 0; j < 4; ++j)
                    acc[i][j] = fmaf(am[i], bm[j], acc[i][j]);
        }
    }
#pragma unroll
    for (int i = 0; i < 4; ++i) {
        int m = m0 + (ty << 2) + i;
#pragma unroll
        for (int j = 0; j < 4; ++j) {
            int n = n0 + (tx << 2) + j;
            float v = acc[i][j];
            if (BIAS) v += bias[n];
            if (ACT == 1) v = fmaxf(v, 0.f);
            else if (ACT == 2) v = tanhf(v);
            else if (ACT == 3) v = (v > 20.f) ? v : log1pf(__expf(v));
            if (ADDDEST) v += C[(size_t)m * ldc + n];
            C[(size_t)m * ldc + n] = v;
        }
    }
}

// ---------------------------------------------------------------------------
__global__ void f2b_k(const float* __restrict__ s, __bf16* __restrict__ d, int n8)
{
    int i = blockIdx.x * 256 + threadIdx.x;
    if (i >= n8) return;
    float4 a = ((const float4*)s)[2 * i], b = ((const float4*)s)[2 * i + 1];
    bf16x8 v;
    v[0] = (__bf16)a.x; v[1] = (__bf16)a.y; v[2] = (__bf16)a.z; v[3] = (__bf16)a.w;
    v[4] = (__bf16)b.x; v[5] = (__bf16)b.y; v[6] = (__bf16)b.z; v[7] = (__bf16)b.w;
    *(bf16x8*)&d[8 * i] = v;
}

// concat data_s|data_l -> bf16 (M x 1024)
__global__ void concat_bf_k(const float* __restrict__ a,
                            const float* __restrict__ b,
                            __bf16* __restrict__ o)
{
    int idx = blockIdx.x * 256 + threadIdx.x;   // 0..524287 (8 elems each)
    int m = idx >> 7, c8 = (idx & 127) << 3;
    const float* src = (c8 < 512) ? &a[(m << 9) + c8] : &b[(m << 9) + c8 - 512];
    float4 x = ((const float4*)src)[0], y = ((const float4*)src)[1];
    bf16x8 v;
    v[0] = (__bf16)x.x; v[1] = (__bf16)x.y; v[2] = (__bf16)x.z; v[3] = (__bf16)x.w;
    v[4] = (__bf16)y.x; v[5] = (__bf16)y.y; v[6] = (__bf16)y.z; v[7] = (__bf16)y.w;
    *(bf16x8*)&o[idx << 3] = v;
}

// LayerNorm over D=512, one block of 128 threads per row. OB: bf16 output.
template <bool OB>
__global__ __launch_bounds__(128) void layernorm_k(
    const float* __restrict__ X, const float* __restrict__ w,
    const float* __restrict__ b, float* __restrict__ Yf, __bf16* __restrict__ Yb)
{
    const int r = blockIdx.x, tid = threadIdx.x;
    const size_t base = ((size_t)r << 9) + (tid << 2);
    const float4 v = *(const float4*)&X[base];
    float s = v.x + v.y + v.z + v.w;
#pragma unroll
    for (int o = 32; o; o >>= 1) s += __shfl_down(s, o, 64);
    __shared__ float red[2];
    if ((tid & 63) == 0) red[tid >> 6] = s;
    __syncthreads();
    const float mean = (red[0] + red[1]) * (1.f / 512.f);
    float dx = v.x - mean, dy = v.y - mean, dz = v.z - mean, dw = v.w - mean;
    float q = dx * dx + dy * dy + dz * dz + dw * dw;
#pragma unroll
    for (int o = 32; o; o >>= 1) q += __shfl_down(q, o, 64);
    __shared__ float red2[2];
    if ((tid & 63) == 0) red2[tid >> 6] = q;
    __syncthreads();
    const float rs = rsqrtf((red2[0] + red2[1]) * (1.f / 512.f) + 1e-5f);
    const float4 wv = *(const float4*)&w[tid << 2];
    const float4 bv = *(const float4*)&b[tid << 2];
    float o0 = dx * rs * wv.x + bv.x;
    float o1 = dy * rs * wv.y + bv.y;
    float o2 = dz * rs * wv.z + bv.z;
    float o3 = dw * rs * wv.w + bv.w;
    if (OB) {
        bf16x4 ov; ov[0] = (__bf16)o0; ov[1] = (__bf16)o1;
        ov[2] = (__bf16)o2; ov[3] = (__bf16)o3;
        *(bf16x4*)&Yb[base] = ov;
    } else {
        float4 ov; ov.x = o0; ov.y = o1; ov.z = o2; ov.w = o3;
        *(float4*)&Yf[base] = ov;
    }
}

// depthwise causal conv (DC=4) + SiLU. X is x-half of XZ (stride 2048).
// writes f32 XC (for scan) and bf16 XCb (for x_proj GEMM). 4 channels/thread.
__global__ void conv_silu_k(const float* __restrict__ XZ,
                            const float* __restrict__ cw,
                            const float* __restrict__ cb,
                            float* __restrict__ XC, __bf16* __restrict__ XCb)
{
    int i = blockIdx.x * 256 + threadIdx.x;      // 0..(4096*256-1)
    int t = i >> 8, d4 = (i & 255) << 2;
    float wt[4][4];
#pragma unroll
    for (int d = 0; d < 4; ++d) {
        float4 w = *(const float4*)&cw[(d4 + d) << 2];
        wt[d][0] = w.x; wt[d][1] = w.y; wt[d][2] = w.z; wt[d][3] = w.w;
    }
    float4 c = *(const float4*)&cb[d4];
    float a0 = c.x, a1 = c.y, a2 = c.z, a3 = c.w;
#pragma unroll
    for (int k = 0; k < 4; ++k) {
        int ts = t + k - 3;
        if (ts >= 0) {
            float4 x = *(const float4*)&XZ[((size_t)ts << 11) + d4];
            a0 = fmaf(x.x, wt[0][k], a0);
            a1 = fmaf(x.y, wt[1][k], a1);
            a2 = fmaf(x.z, wt[2][k], a2);
            a3 = fmaf(x.w, wt[3][k], a3);
        }
    }
    a0 *= 1.f / (1.f + __expf(-a0));
    a1 *= 1.f / (1.f + __expf(-a1));
    a2 *= 1.f / (1.f + __expf(-a2));
    a3 *= 1.f / (1.f + __expf(-a3));
    size_t o = ((size_t)t << 10) + d4;
    float4 of; of.x = a0; of.y = a1; of.z = a2; of.w = a3;
    *(float4*)&XC[o] = of;
    bf16x4 ob; ob[0] = (__bf16)a0; ob[1] = (__bf16)a1;
    ob[2] = (__bf16)a2; ob[3] = (__bf16)a3;
    *(bf16x4*)&XCb[o] = ob;
}

// ---------------------------------------------------------------------------
// Selective scan, chunked (3 passes). f32 throughout.
// ---------------------------------------------------------------------------
__global__ __launch_bounds__(256) void scanA_k(
    const float* __restrict__ dt, const float* __restrict__ xc,
    const float* __restrict__ xdbl, const float* __restrict__ Alog,
    float* __restrict__ sP, float* __restrict__ sH)
{
    const int d = blockIdx.x * 256 + threadIdx.x;
    const int c = blockIdx.y;
    __shared__ float Bs[CL][DS];
    for (int idx = threadIdx.x; idx < CL * DS; idx += 256) {
        int t = idx / DS, s = idx % DS;
        Bs[t][s] = xdbl[(size_t)(c * CL + t) * 64 + 32 + s];
    }
    __syncthreads();
    float As[DS], h[DS], P[DS];
#pragma unroll
    for (int s = 0; s < DS; ++s) {
        As[s] = -__expf(Alog[d * DS + s]);
        h[s] = 0.f; P[s] = 1.f;
    }
    for (int t = 0; t < CL; ++t) {
        size_t tg = (size_t)(c * CL + t);
        float dtv = dt[(tg << 10) + d];
        float xv  = xc[(tg << 10) + d];
        float dx = dtv * xv;
#pragma unroll
        for (int s = 0; s < DS; ++s) {
            float a = __expf(dtv * As[s]);
            h[s] = fmaf(a, h[s], dx * Bs[t][s]);
            P[s] *= a;
        }
    }
    size_t base = ((size_t)c * DI + d) * DS;
#pragma unroll
    for (int s = 0; s < DS; ++s) { sP[base + s] = P[s]; sH[base + s] = h[s]; }
}

__global__ __launch_bounds__(256) void scanB_k(
    const float* __restrict__ sP, const float* __restrict__ sH,
    float* __restrict__ Hin)
{
    int p = blockIdx.x * 256 + threadIdx.x;
    float run = 0.f;
    for (int c = 0; c < NCHK; ++c) {
        size_t idx = (size_t)c * DI * DS + p;
        Hin[idx] = run;
        run = fmaf(sP[idx], run, sH[idx]);
    }
}

__global__ __launch_bounds__(256) void scanC_k(
    const float* __restrict__ dt, const float* __restrict__ xc,
    const float* __restrict__ xdbl, const float* __restrict__ Alog,
    const float* __restrict__ Dp, const float* __restrict__ XZ,
    const float* __restrict__ Hin, __bf16* __restrict__ yz)
{
    const int d = blockIdx.x * 256 + threadIdx.x;
    const int c = blockIdx.y;
    __shared__ float Bs[CL][DS], Cs[CL][DS];
    for (int idx = threadIdx.x; idx < CL * DS; idx += 256) {
        int t = idx / DS, s = idx % DS;
        Bs[t][s] = xdbl[(size_t)(c * CL + t) * 64 + 32 + s];
        Cs[t][s] = xdbl[(size_t)(c * CL + t) * 64 + 48 + s];
    }
    __syncthreads();
    float As[DS], h[DS];
    size_t hbase = ((size_t)c * DI + d) * DS;
#pragma unroll
    for (int s = 0; s < DS; ++s) {
        As[s] = -__expf(Alog[d * DS + s]);
        h[s] = Hin[hbase + s];
    }
    const float Dd = Dp[d];
    for (int t = 0; t < CL; ++t) {
        size_t tg = (size_t)(c * CL + t);
        float dtv = dt[(tg << 10) + d];
        float xv  = xc[(tg << 10) + d];
        float dx = dtv * xv;
        float y = 0.f;
#pragma unroll
        for (int s = 0; s < DS; ++s) {
            float a = __expf(dtv * As[s]);
            h[s] = fmaf(a, h[s], dx * Bs[t][s]);
            y = fmaf(h[s], Cs[t][s], y);
        }
        y = fmaf(Dd, xv, y);
        float zv = XZ[(tg << 11) + 1024 + d];
        float sg = 1.f / (1.f + __expf(-zv));
        yz[(tg << 10) + d] = (__bf16)(y * (zv * sg));
    }
}

// ---------------------------------------------------------------------------
// Attention pooling tail
// ---------------------------------------------------------------------------
__global__ void score_k(const float* __restrict__ At,
                        const float* __restrict__ w2,
                        const float* __restrict__ b2,
                        float* __restrict__ sc)
{
    int t = blockIdx.x * 256 + threadIdx.x;
    const float4* a = (const float4*)(At + ((size_t)t << 7));
    const float4* w = (const float4*)w2;
    float acc = 0.f;
#pragma unroll
    for (int j = 0; j < 32; ++j) {
        float4 av = a[j], wv = w[j];
        acc += av.x * wv.x + av.y * wv.y + av.z * wv.z + av.w * wv.w;
    }
    sc[t] = acc + b2[0];
}

__global__ __launch_bounds__(256) void softmax_k(const float* __restrict__ s,
                                                 float* __restrict__ p)
{
    const int tid = threadIdx.x;
    float vals[16];
#pragma unroll
    for (int i = 0; i < 4; ++i) {
        float4 v = *(const float4*)&s[(tid << 4) + (i << 2)];
        vals[i * 4 + 0] = v.x; vals[i * 4 + 1] = v.y;
        vals[i * 4 + 2] = v.z; vals[i * 4 + 3] = v.w;
    }
    float mx = -1e30f;
#pragma unroll
    for (int i = 0; i < 16; ++i) mx = fmaxf(mx, vals[i]);
#pragma unroll
    for (int o = 32; o; o >>= 1) mx = fmaxf(mx, __shfl_xor(mx, o, 64));
    __shared__ float red[4];
    if ((tid & 63) == 0) red[tid >> 6] = mx;
    __syncthreads();
    mx = fmaxf(fmaxf(red[0], red[1]), fmaxf(red[2], red[3]));
    float sum = 0.f, e[16];
#pragma unroll
    for (int i = 0; i < 16; ++i) { e[i] = __expf(vals[i] - mx); sum += e[i]; }
#pragma unroll
    for (int o = 32; o; o >>= 1) sum += __shfl_xor(sum, o, 64);
    __syncthreads();
    if ((tid & 63) == 0) red[tid >> 6] = sum;
    __syncthreads();
    sum = red[0] + red[1] + red[2] + red[3];
    float inv = 1.f / sum;
#pragma unroll
    for (int i = 0; i < 4; ++i) {
        float4 ov;
        ov.x = e[i * 4 + 0] * inv; ov.y = e[i * 4 + 1] * inv;
        ov.z = e[i * 4 + 2] * inv; ov.w = e[i * 4 + 3] * inv;
        *(float4*)&p[(tid << 4) + (i << 2)] = ov;
    }
}

__global__ void pool_partial_k(const float* __restrict__ prob,
                               const float* __restrict__ hln,
                               float* __restrict__ part)
{
    int j = blockIdx.x * 256 + threadIdx.x;
    int c = blockIdx.y;
    float acc = 0.f;
    for (int t = c * 128; t < (c + 1) * 128; ++t)
        acc = fmaf(prob[t], hln[((size_t)t << 9) + j], acc);
    part[c * 512 + j] = acc;
}

__global__ void pool_reduce_k(const float* __restrict__ part,
                              float* __restrict__ hp)
{
    int j = blockIdx.x * 256 + threadIdx.x;
    float acc = 0.f;
    for (int c = 0; c < 32; ++c) acc += part[c * 512 + j];
    hp[j] = acc;
}

__global__ __launch_bounds__(256) void final_head_k(
    const float* __restrict__ hp, const float* __restrict__ cls_w,
    const float* __restrict__ cls_b, const int* __restrict__ label,
    float* __restrict__ out)
{
    const int w = threadIdx.x >> 6, lane = threadIdx.x & 63;
    float acc = 0.f;
    for (int k = lane; k < 512; k += 64) acc += hp[k] * cls_w[w * 512 + k];
#pragma unroll
    for (int o = 32; o; o >>= 1) acc += __shfl_down(acc, o, 64);
    __shared__ float lg[4];
    if (lane == 0) lg[w] = acc + cls_b[w];
    __syncthreads();
    if (threadIdx.x == 0) {
        float lce[4];
        for (int c = 0; c < 4; ++c) {
            float z = lg[c];
            float hz = 1.f / (1.f + expf(-z));
            float pc = fminf(fmaxf(hz, 1e-6f), 1.f - 1e-6f);
            lce[c] = logf(pc) - log1pf(-pc);
        }
        float mx = fmaxf(fmaxf(lce[0], lce[1]), fmaxf(lce[2], lce[3]));
        float se = 0.f;
        for (int c = 0; c < 4; ++c) se += expf(lce[c] - mx);
        for (int c = 0; c < 4; ++c) out[c] = lce[c];
        for (int c = 0; c < 4; ++c) out[4 + c] = expf(lce[c] - mx) / se;
        int lb = label[0];
        out[8] = -(lce[lb] - mx - logf(se));
    }
}

// ---------------------------------------------------------------------------
extern "C" void kernel_launch(void* const* d_in, const int* in_sizes, int n_in,
                              void* d_out, int out_size, void* d_ws, size_t ws_size,
                              hipStream_t stream)
{
    const float* data_s   = (const float*)d_in[0];
    const float* data_l   = (const float*)d_in[1];
    const int*   label    = (const int*)d_in[3];
    const float* fc1_w    = (const float*)d_in[4];
    const float* fc1_b    = (const float*)d_in[5];
    const float* ln_w     = (const float*)d_in[6];
    const float* ln_b     = (const float*)d_in[7];
    const float* in_proj_w= (const float*)d_in[8];
    const float* conv_w   = (const float*)d_in[9];
    const float* conv_b   = (const float*)d_in[10];
    const float* x_proj_w = (const float*)d_in[11];
    const float* dt_proj_w= (const float*)d_in[12];
    const float* dt_proj_b= (const float*)d_in[13];
    const float* A_log    = (const float*)d_in[14];
    const float* D_param  = (const float*)d_in[15];
    const float* out_proj_w=(const float*)d_in[16];
    const float* norm_w   = (const float*)d_in[17];
    const float* norm_b   = (const float*)d_in[18];
    const float* attn_w1  = (const float*)d_in[19];
    const float* attn_b1  = (const float*)d_in[20];
    const float* attn_w2  = (const float*)d_in[21];
    const float* attn_b2  = (const float*)d_in[22];
    const float* cls_w    = (const float*)d_in[23];
    const float* cls_b    = (const float*)d_in[24];
    float* out = (float*)d_out;

    // ---- workspace layout ----
    float* ws = (float*)d_ws;
    size_t off = 0;
    float* h    = ws + off; off += (size_t)L_SEQ * DMODEL;      // 2M
    float* hn   = ws + off; off += (size_t)L_SEQ * DMODEL;      // 2M (final LN, f32)
    float* XZ   = ws + off; off += (size_t)L_SEQ * 2 * DI;      // 8M
    float* XC   = ws + off; off += (size_t)L_SEQ * DI;          // 4M
    float* dtb  = ws + off; off += (size_t)L_SEQ * DI;          // 4M
    float* xdbl = ws + off; off += (size_t)L_SEQ * 64;          // 256K
    float* sP   = ws + off; off += (size_t)NCHK * DI * DS;      // 1M
    float* sH   = ws + off; off += (size_t)NCHK * DI * DS;      // 1M
    float* Hin  = ws + off; off += (size_t)NCHK * DI * DS;      // 1M
    float* At   = ws + off; off += (size_t)L_SEQ * 128;         // 512K
    float* sc   = ws + off; off += L_SEQ;
    float* pb   = ws + off; off += L_SEQ;
    float* part = ws + off; off += 32 * 512;
    float* hp   = ws + off; off += 512;

    __bf16* bws = (__bf16*)(ws + off);
    size_t boff = 0;
    __bf16* bfA   = bws + boff; boff += (size_t)L_SEQ * DIN;    // Acat_bf / XCb / yzb
    __bf16* hnb   = bws + boff; boff += (size_t)L_SEQ * DMODEL;
    __bf16* wfc1b = bws + boff; boff += (size_t)DMODEL * DIN;
    __bf16* winb  = bws + boff; boff += (size_t)2 * 2 * DI * DMODEL;
    __bf16* wxpb  = bws + boff; boff += (size_t)2 * 64 * DI;
    __bf16* woutb = bws + boff; boff += (size_t)2 * DMODEL * DI;
    if (ws_size < off * sizeof(float) + boff * sizeof(__bf16)) return;

    // ---- weight conversions (per call; ~7 MB traffic) ----
    f2b_k<<<(DMODEL * DIN / 8 + 255) / 256, 256, 0, stream>>>(fc1_w, wfc1b, DMODEL * DIN / 8);
    f2b_k<<<(2 * 2 * DI * DMODEL / 8 + 255) / 256, 256, 0, stream>>>(in_proj_w, winb, 2 * 2 * DI * DMODEL / 8);
    f2b_k<<<(2 * 64 * DI / 8 + 255) / 256, 256, 0, stream>>>(x_proj_w, wxpb, 2 * 64 * DI / 8);
    f2b_k<<<(2 * DMODEL * DI / 8 + 255) / 256, 256, 0, stream>>>(out_proj_w, woutb, 2 * DMODEL * DI / 8);

    // h = relu(concat @ fc1_w.T + b)
    concat_bf_k<<<L_SEQ * DIN / 8 / 256, 256, 0, stream>>>(data_s, data_l, bfA);
    gemm_mfma<64, 1, true, false><<<dim3(DMODEL / 64, L_SEQ / 128), 256, 0, stream>>>(
        bfA, DIN, wfc1b, DIN, fc1_b, h, DMODEL, DIN);

    for (int i = 0; i < 2; ++i) {
        const __bf16* inw = winb + (size_t)i * 2 * DI * DMODEL;
        const float* cwi = conv_w + (size_t)i * DI * DC;
        const float* cbi = conv_b + (size_t)i * DI;
        const __bf16* xpw = wxpb + (size_t)i * 64 * DI;
        const float* dtw = dt_proj_w + (size_t)i * DI * DTR;
        const float* dtbv= dt_proj_b + (size_t)i * DI;
        const float* Alg = A_log + (size_t)i * DI * DS;
        const float* Dpi = D_param + (size_t)i * DI;
        const __bf16* owi = woutb + (size_t)i * DMODEL * DI;

        layernorm_k<true><<<L_SEQ, 128, 0, stream>>>(h, ln_w + i * DMODEL, ln_b + i * DMODEL, nullptr, hnb);
        // XZ = hn @ inw.T  (N=2048 fused x|z)
        gemm_mfma<128, 0, false, false><<<dim3(2 * DI / 128, L_SEQ / 128), 256, 0, stream>>>(
            hnb, DMODEL, inw, DMODEL, nullptr, XZ, 2 * DI, DMODEL);
        conv_silu_k<<<L_SEQ * DI / 4 / 256, 256, 0, stream>>>(XZ, cwi, cbi, XC, bfA);
        // xdbl = XC @ xpw.T (N=64)
        gemm_mfma<64, 0, false, false><<<dim3(1, L_SEQ / 128), 256, 0, stream>>>(
            bfA, DI, xpw, DI, nullptr, xdbl, 64, DI);
        // dt = softplus(xdbl[:, :32] @ dtw.T + dtb)  (f32, K=32)
        gemm_bt<3, true, false><<<dim3(DI / 64, L_SEQ / 64), 256, 0, stream>>>(
            xdbl, 64, dtw, dtbv, dtb, DI, DTR);
        // selective scan (chunked)
        scanA_k<<<dim3(DI / 256, NCHK), 256, 0, stream>>>(dtb, XC, xdbl, Alg, sP, sH);
        scanB_k<<<DI * DS / 256, 256, 0, stream>>>(sP, sH, Hin);
        scanC_k<<<dim3(DI / 256, NCHK), 256, 0, stream>>>(dtb, XC, xdbl, Alg, Dpi, XZ, Hin, bfA);
        // h += yz @ owi.T
        gemm_mfma<64, 0, false, true><<<dim3(DMODEL / 64, L_SEQ / 128), 256, 0, stream>>>(
            bfA, DI, owi, DI, nullptr, h, DMODEL, DI);
    }

    // final LN (f32), attention pooling, head
    layernorm_k<false><<<L_SEQ, 128, 0, stream>>>(h, norm_w, norm_b, hn, nullptr);
    gemm_bt<2, true, false><<<dim3(128 / 64, L_SEQ / 64), 256, 0, stream>>>(
        hn, DMODEL, attn_w1, attn_b1, At, 128, DMODEL);
    score_k<<<L_SEQ / 256, 256, 0, stream>>>(At, attn_w2, attn_b2, sc);
    softmax_k<<<1, 256, 0, stream>>>(sc, pb);
    pool_partial_k<<<dim3(2, 32), 256, 0, stream>>>(pb, hn, part);
    pool_reduce_k<<<2, 256, 0, stream>>>(part, hp);
    final_head_k<<<1, 256, 0, stream>>>(hp, cls_w, cls_b, label, out);
}

// Round 3
// 442.176 us; speedup vs baseline: 2.0179x; 1.1491x over previous
//
#include <hip/hip_runtime.h>
#include <math.h>

#define L_SEQ 4096
#define DMODEL 512
#define DIN    1024
#define DI     1024
#define DS     16
#define DC     4
#define DTR    32
#define NCHK   256
#define CL     16

typedef __bf16 bf16x8 __attribute__((ext_vector_type(8)));
typedef __bf16 bf16x4 __attribute__((ext_vector_type(4)));
typedef float floatx4 __attribute__((ext_vector_type(4)));

__device__ __forceinline__ void gl2lds16(const __bf16* g, __bf16* l) {
    __builtin_amdgcn_global_load_lds(
        (const __attribute__((address_space(1))) void*)g,
        (__attribute__((address_space(3))) void*)l, 16, 0, 0);
}

// ---------------------------------------------------------------------------
// bf16 MFMA GEMM. A: M x lda bf16. W: N x ldw bf16. BM=128, BK=32, 256 thr.
// BN=128: 4 waves 2x2 (64x64 each). BN=64: 4 waves stacked in M (32x64 each).
// OUTBF: write bf16 to Cb, else f32 to C (ADDDEST only with f32).
// ---------------------------------------------------------------------------
template <int BN, int ACT, bool BIAS, bool ADDDEST, bool OUTBF>
__global__ __launch_bounds__(256) void gemm_mfma(
    const __bf16* __restrict__ A, int lda,
    const __bf16* __restrict__ W, int ldw,
    const float* __restrict__ bias,
    float* __restrict__ C, __bf16* __restrict__ Cb, int ldc, int K)
{
    __shared__ __align__(16) __bf16 sA[128 * 32];
    __shared__ __align__(16) __bf16 sB[BN * 32];
    const int tid = threadIdx.x;
    const int wid = tid >> 6, lane = tid & 63;
    const int m0 = blockIdx.y * 128, n0 = blockIdx.x * BN;

    constexpr int MR = (BN == 128) ? 4 : 2;
    constexpr int NR = 4;
    const int wrow = (BN == 128) ? (wid >> 1) * 64 : wid * 32;
    const int wcol = (BN == 128) ? (wid & 1) * 64 : 0;

    const int srowA0 = wid * 32 + (lane >> 2);
    const int scol   = (lane & 3) * 8;
    const __bf16* aSrc0 = A + (size_t)(m0 + srowA0) * lda + scol;
    const __bf16* aSrc1 = aSrc0 + 16 * (size_t)lda;
    __bf16* aDst0 = &sA[wid * 1024];
    __bf16* aDst1 = &sA[wid * 1024 + 512];

    const __bf16* bSrc0;
    const __bf16* bSrc1 = nullptr;
    __bf16* bDst0;
    __bf16* bDst1 = nullptr;
    if (BN == 128) {
        bSrc0 = W + (size_t)(n0 + wid * 32 + (lane >> 2)) * ldw + scol;
        bSrc1 = bSrc0 + 16 * (size_t)ldw;
        bDst0 = &sB[wid * 1024];
        bDst1 = &sB[wid * 1024 + 512];
    } else {
        bSrc0 = W + (size_t)(n0 + wid * 16 + (lane >> 2)) * ldw + scol;
        bDst0 = &sB[wid * 512];
    }

    floatx4 acc[MR][NR] = {};
    const int fr = lane & 15;
    const int fk = (lane >> 4) * 8;

    for (int k0 = 0; k0 < K; k0 += 32) {
        __syncthreads();
        gl2lds16(aSrc0 + k0, aDst0);
        gl2lds16(aSrc1 + k0, aDst1);
        gl2lds16(bSrc0 + k0, bDst0);
        if (BN == 128) gl2lds16(bSrc1 + k0, bDst1);
        __syncthreads();
        bf16x8 af[MR], bfv[NR];
#pragma unroll
        for (int i = 0; i < MR; ++i)
            af[i] = *(const bf16x8*)&sA[(wrow + i * 16 + fr) * 32 + fk];
#pragma unroll
        for (int j = 0; j < NR; ++j)
            bfv[j] = *(const bf16x8*)&sB[(wcol + j * 16 + fr) * 32 + fk];
#pragma unroll
        for (int i = 0; i < MR; ++i)
#pragma unroll
            for (int j = 0; j < NR; ++j)
                acc[i][j] = __builtin_amdgcn_mfma_f32_16x16x32_bf16(
                    af[i], bfv[j], acc[i][j], 0, 0, 0);
    }

#pragma unroll
    for (int i = 0; i < MR; ++i)
#pragma unroll
        for (int j = 0; j < NR; ++j) {
            const int n = n0 + wcol + j * 16 + fr;
            float bv = 0.f;
            if (BIAS) bv = bias[n];
#pragma unroll
            for (int r = 0; r < 4; ++r) {
                const int m = m0 + wrow + i * 16 + (lane >> 4) * 4 + r;
                float v = acc[i][j][r] + bv;
                if (ACT == 1) v = fmaxf(v, 0.f);
                const size_t idx = (size_t)m * ldc + n;
                if (OUTBF) {
                    Cb[idx] = (__bf16)v;
                } else {
                    if (ADDDEST) v += C[idx];
                    C[idx] = v;
                }
            }
        }
}

// ---------------------------------------------------------------------------
// f32 tiled GEMM for small ops. ACT: 0 none 1 relu 2 tanh 3 softplus.
// ---------------------------------------------------------------------------
template <int ACT, bool BIAS, bool OUTBF>
__global__ __launch_bounds__(256) void gemm_bt(
    const float* __restrict__ A, int lda,
    const float* __restrict__ W,
    const float* __restrict__ bias,
    float* __restrict__ C, __bf16* __restrict__ Cb, int ldc, int K)
{
    __shared__ float sA[16][68];
    __shared__ float sB[16][68];
    const int tid = threadIdx.x;
    const int tx = tid & 15, ty = tid >> 4;
    const int m0 = blockIdx.y * 64, n0 = blockIdx.x * 64;
    const int lr = tid >> 2;
    const int lk = (tid & 3) << 2;
    float acc[4][4] = {};
    const float* Ap = A + (size_t)(m0 + lr) * lda + lk;
    const float* Wp = W + (size_t)(n0 + lr) * K + lk;
    for (int k0 = 0; k0 < K; k0 += 16) {
        float4 a4 = *(const float4*)(Ap + k0);
        float4 b4 = *(const float4*)(Wp + k0);
        __syncthreads();
        sA[lk + 0][lr] = a4.x; sA[lk + 1][lr] = a4.y;
        sA[lk + 2][lr] = a4.z; sA[lk + 3][lr] = a4.w;
        sB[lk + 0][lr] = b4.x; sB[lk + 1][lr] = b4.y;
        sB[lk + 2][lr] = b4.z; sB[lk + 3][lr] = b4.w;
        __syncthreads();
#pragma unroll
        for (int kk = 0; kk < 16; ++kk) {
            float4 av = *(const float4*)&sA[kk][ty << 2];
            float4 bv = *(const float4*)&sB[kk][tx << 2];
            float am[4] = {av.x, av.y, av.z, av.w};
            float bm[4] = {bv.x, bv.y, bv.z, bv.w};
#pragma unroll
            for (int i = 0; i < 4; ++i)
#pragma unroll
                for (int j = 0; j < 4; ++j)
                    acc[i][j] = fmaf(am[i], bm[j], acc[i][j]);
        }
    }
#pragma unroll
    for (int i = 0; i < 4; ++i) {
        int m = m0 + (ty << 2) + i;
#pragma unroll
        for (int j = 0; j < 4; ++j) {
            int n = n0 + (tx << 2) + j;
            float v = acc[i][j];
            if (BIAS) v += bias[n];
            if (ACT == 1) v = fmaxf(v, 0.f);
            else if (ACT == 2) v = tanhf(v);
            else if (ACT == 3) v = (v > 20.f) ? v : log1pf(__expf(v));
            if (OUTBF) Cb[(size_t)m * ldc + n] = (__bf16)v;
            else       C[(size_t)m * ldc + n] = v;
        }
    }
}

// ---------------------------------------------------------------------------
// convert 4 f32 buffers to bf16 in one launch (counts are 8-elem units)
__global__ void f2b4_k(const float* __restrict__ s0, __bf16* __restrict__ d0, int n0,
                       const float* __restrict__ s1, __bf16* __restrict__ d1, int n1,
                       const float* __restrict__ s2, __bf16* __restrict__ d2, int n2,
                       const float* __restrict__ s3, __bf16* __restrict__ d3, int n3)
{
    int i = blockIdx.x * 256 + threadIdx.x;
    const float* s; __bf16* d; int base;
    if (i < n0) { s = s0; d = d0; base = i; }
    else if (i < n0 + n1) { s = s1; d = d1; base = i - n0; }
    else if (i < n0 + n1 + n2) { s = s2; d = d2; base = i - n0 - n1; }
    else if (i < n0 + n1 + n2 + n3) { s = s3; d = d3; base = i - n0 - n1 - n2; }
    else return;
    float4 a = ((const float4*)s)[2 * base], b = ((const float4*)s)[2 * base + 1];
    bf16x8 v;
    v[0] = (__bf16)a.x; v[1] = (__bf16)a.y; v[2] = (__bf16)a.z; v[3] = (__bf16)a.w;
    v[4] = (__bf16)b.x; v[5] = (__bf16)b.y; v[6] = (__bf16)b.z; v[7] = (__bf16)b.w;
    *(bf16x8*)&d[8 * base] = v;
}

__global__ void concat_bf_k(const float* __restrict__ a,
                            const float* __restrict__ b,
                            __bf16* __restrict__ o)
{
    int idx = blockIdx.x * 256 + threadIdx.x;
    int m = idx >> 7, c8 = (idx & 127) << 3;
    const float* src = (c8 < 512) ? &a[(m << 9) + c8] : &b[(m << 9) + c8 - 512];
    float4 x = ((const float4*)src)[0], y = ((const float4*)src)[1];
    bf16x8 v;
    v[0] = (__bf16)x.x; v[1] = (__bf16)x.y; v[2] = (__bf16)x.z; v[3] = (__bf16)x.w;
    v[4] = (__bf16)y.x; v[5] = (__bf16)y.y; v[6] = (__bf16)y.z; v[7] = (__bf16)y.w;
    *(bf16x8*)&o[idx << 3] = v;
}

// LayerNorm over D=512, one 128-thread block per row. OB: bf16 output.
template <bool OB>
__global__ __launch_bounds__(128) void layernorm_k(
    const float* __restrict__ X, const float* __restrict__ w,
    const float* __restrict__ b, float* __restrict__ Yf, __bf16* __restrict__ Yb)
{
    const int r = blockIdx.x, tid = threadIdx.x;
    const size_t base = ((size_t)r << 9) + (tid << 2);
    const float4 v = *(const float4*)&X[base];
    float s = v.x + v.y + v.z + v.w;
#pragma unroll
    for (int o = 32; o; o >>= 1) s += __shfl_down(s, o, 64);
    __shared__ float red[2];
    if ((tid & 63) == 0) red[tid >> 6] = s;
    __syncthreads();
    const float mean = (red[0] + red[1]) * (1.f / 512.f);
    float dx = v.x - mean, dy = v.y - mean, dz = v.z - mean, dw = v.w - mean;
    float q = dx * dx + dy * dy + dz * dz + dw * dw;
#pragma unroll
    for (int o = 32; o; o >>= 1) q += __shfl_down(q, o, 64);
    __shared__ float red2[2];
    if ((tid & 63) == 0) red2[tid >> 6] = q;
    __syncthreads();
    const float rs = rsqrtf((red2[0] + red2[1]) * (1.f / 512.f) + 1e-5f);
    const float4 wv = *(const float4*)&w[tid << 2];
    const float4 bv = *(const float4*)&b[tid << 2];
    float o0 = dx * rs * wv.x + bv.x;
    float o1 = dy * rs * wv.y + bv.y;
    float o2 = dz * rs * wv.z + bv.z;
    float o3 = dw * rs * wv.w + bv.w;
    if (OB) {
        bf16x4 ov; ov[0] = (__bf16)o0; ov[1] = (__bf16)o1;
        ov[2] = (__bf16)o2; ov[3] = (__bf16)o3;
        *(bf16x4*)&Yb[base] = ov;
    } else {
        float4 ov; ov.x = o0; ov.y = o1; ov.z = o2; ov.w = o3;
        *(float4*)&Yf[base] = ov;
    }
}

// depthwise causal conv (DC=4) + SiLU. XZb bf16 (row stride 2048), x half.
__global__ void conv_silu_k(const __bf16* __restrict__ XZb,
                            const float* __restrict__ cw,
                            const float* __restrict__ cb,
                            __bf16* __restrict__ XCb)
{
    int i = blockIdx.x * 256 + threadIdx.x;      // 0..(4096*256-1)
    int t = i >> 8, d4 = (i & 255) << 2;
    float wt[4][4];
#pragma unroll
    for (int d = 0; d < 4; ++d) {
        float4 w = *(const float4*)&cw[(d4 + d) << 2];
        wt[d][0] = w.x; wt[d][1] = w.y; wt[d][2] = w.z; wt[d][3] = w.w;
    }
    float4 c = *(const float4*)&cb[d4];
    float a0 = c.x, a1 = c.y, a2 = c.z, a3 = c.w;
#pragma unroll
    for (int k = 0; k < 4; ++k) {
        int ts = t + k - 3;
        if (ts >= 0) {
            bf16x4 x = *(const bf16x4*)&XZb[((size_t)ts << 11) + d4];
            a0 = fmaf((float)x[0], wt[0][k], a0);
            a1 = fmaf((float)x[1], wt[1][k], a1);
            a2 = fmaf((float)x[2], wt[2][k], a2);
            a3 = fmaf((float)x[3], wt[3][k], a3);
        }
    }
    a0 *= 1.f / (1.f + __expf(-a0));
    a1 *= 1.f / (1.f + __expf(-a1));
    a2 *= 1.f / (1.f + __expf(-a2));
    a3 *= 1.f / (1.f + __expf(-a3));
    bf16x4 ob; ob[0] = (__bf16)a0; ob[1] = (__bf16)a1;
    ob[2] = (__bf16)a2; ob[3] = (__bf16)a3;
    *(bf16x4*)&XCb[((size_t)t << 10) + d4] = ob;
}

// ---------------------------------------------------------------------------
// Selective scan, chunked (3 passes). CL=16, NCHK=256 -> 16 waves/CU.
// ---------------------------------------------------------------------------
__global__ __launch_bounds__(256) void scanA_k(
    const __bf16* __restrict__ dt, const __bf16* __restrict__ xc,
    const float* __restrict__ xdbl, const float* __restrict__ Alog,
    __bf16* __restrict__ sP, __bf16* __restrict__ sH)
{
    const int d = blockIdx.x * 256 + threadIdx.x;
    const int c = blockIdx.y;
    __shared__ float Bs[CL][DS];
    {
        int idx = threadIdx.x;           // CL*DS == 256
        int t = idx >> 4, s = idx & 15;
        Bs[t][s] = xdbl[(size_t)(c * CL + t) * 64 + 32 + s];
    }
    __syncthreads();
    float As[DS], h[DS];
#pragma unroll
    for (int s = 0; s < DS; ++s) {
        As[s] = -__expf(Alog[d * DS + s]);
        h[s] = 0.f;
    }
    float sumdt = 0.f;
    for (int t = 0; t < CL; ++t) {
        size_t tg = (size_t)(c * CL + t);
        float dtv = (float)dt[(tg << 10) + d];
        float xv  = (float)xc[(tg << 10) + d];
        float dx = dtv * xv;
        sumdt += dtv;
#pragma unroll
        for (int s = 0; s < DS; ++s) {
            float a = __expf(dtv * As[s]);
            h[s] = fmaf(a, h[s], dx * Bs[t][s]);
        }
    }
    size_t base = ((size_t)c * DI + d) * DS;
#pragma unroll
    for (int s = 0; s < DS; ++s) {
        sP[base + s] = (__bf16)__expf(As[s] * sumdt);
        sH[base + s] = (__bf16)h[s];
    }
}

__global__ __launch_bounds__(64) void scanB_k(
    const __bf16* __restrict__ sP, const __bf16* __restrict__ sH,
    __bf16* __restrict__ Hin)
{
    int p = blockIdx.x * 64 + threadIdx.x;       // 16384 (d,s) pairs
    float run = 0.f;
#pragma unroll 4
    for (int c = 0; c < NCHK; ++c) {
        size_t idx = (size_t)c * DI * DS + p;
        Hin[idx] = (__bf16)run;
        run = fmaf((float)sP[idx], run, (float)sH[idx]);
    }
}

__global__ __launch_bounds__(256) void scanC_k(
    const __bf16* __restrict__ dt, const __bf16* __restrict__ xc,
    const float* __restrict__ xdbl, const float* __restrict__ Alog,
    const float* __restrict__ Dp, const __bf16* __restrict__ XZb,
    const __bf16* __restrict__ Hin, __bf16* __restrict__ yz)
{
    const int d = blockIdx.x * 256 + threadIdx.x;
    const int c = blockIdx.y;
    __shared__ float Bs[CL][DS], Cs[CL][DS];
    {
        int idx = threadIdx.x;           // CL*DS == 256
        int t = idx >> 4, s = idx & 15;
        Bs[t][s] = xdbl[(size_t)(c * CL + t) * 64 + 32 + s];
        Cs[t][s] = xdbl[(size_t)(c * CL + t) * 64 + 48 + s];
    }
    __syncthreads();
    float As[DS], h[DS];
    size_t hbase = ((size_t)c * DI + d) * DS;
#pragma unroll
    for (int s = 0; s < DS; ++s) {
        As[s] = -__expf(Alog[d * DS + s]);
        h[s] = (float)Hin[hbase + s];
    }
    const float Dd = Dp[d];
    for (int t = 0; t < CL; ++t) {
        size_t tg = (size_t)(c * CL + t);
        float dtv = (float)dt[(tg << 10) + d];
        float xv  = (float)xc[(tg << 10) + d];
        float dx = dtv * xv;
        float y = 0.f;
#pragma unroll
        for (int s = 0; s < DS; ++s) {
            float a = __expf(dtv * As[s]);
            h[s] = fmaf(a, h[s], dx * Bs[t][s]);
            y = fmaf(h[s], Cs[t][s], y);
        }
        y = fmaf(Dd, xv, y);
        float zv = (float)XZb[(tg << 11) + 1024 + d];
        float sg = 1.f / (1.f + __expf(-zv));
        yz[(tg << 10) + d] = (__bf16)(y * (zv * sg));
    }
}

// ---------------------------------------------------------------------------
// Attention pooling tail
// ---------------------------------------------------------------------------
__global__ void score_k(const float* __restrict__ At,
                        const float* __restrict__ w2,
                        const float* __restrict__ b2,
                        float* __restrict__ sc)
{
    int t = blockIdx.x * 256 + threadIdx.x;
    const float4* a = (const float4*)(At + ((size_t)t << 7));
    const float4* w = (const float4*)w2;
    float acc = 0.f;
#pragma unroll
    for (int j = 0; j < 32; ++j) {
        float4 av = a[j], wv = w[j];
        acc += av.x * wv.x + av.y * wv.y + av.z * wv.z + av.w * wv.w;
    }
    sc[t] = acc + b2[0];
}

__global__ __launch_bounds__(256) void softmax_k(const float* __restrict__ s,
                                                 float* __restrict__ p)
{
    const int tid = threadIdx.x;
    float vals[16];
#pragma unroll
    for (int i = 0; i < 4; ++i) {
        float4 v = *(const float4*)&s[(tid << 4) + (i << 2)];
        vals[i * 4 + 0] = v.x; vals[i * 4 + 1] = v.y;
        vals[i * 4 + 2] = v.z; vals[i * 4 + 3] = v.w;
    }
    float mx = -1e30f;
#pragma unroll
    for (int i = 0; i < 16; ++i) mx = fmaxf(mx, vals[i]);
#pragma unroll
    for (int o = 32; o; o >>= 1) mx = fmaxf(mx, __shfl_xor(mx, o, 64));
    __shared__ float red[4];
    if ((tid & 63) == 0) red[tid >> 6] = mx;
    __syncthreads();
    mx = fmaxf(fmaxf(red[0], red[1]), fmaxf(red[2], red[3]));
    float sum = 0.f, e[16];
#pragma unroll
    for (int i = 0; i < 16; ++i) { e[i] = __expf(vals[i] - mx); sum += e[i]; }
#pragma unroll
    for (int o = 32; o; o >>= 1) sum += __shfl_xor(sum, o, 64);
    __syncthreads();
    if ((tid & 63) == 0) red[tid >> 6] = sum;
    __syncthreads();
    sum = red[0] + red[1] + red[2] + red[3];
    float inv = 1.f / sum;
#pragma unroll
    for (int i = 0; i < 4; ++i) {
        float4 ov;
        ov.x = e[i * 4 + 0] * inv; ov.y = e[i * 4 + 1] * inv;
        ov.z = e[i * 4 + 2] * inv; ov.w = e[i * 4 + 3] * inv;
        *(float4*)&p[(tid << 4) + (i << 2)] = ov;
    }
}

__global__ void pool_partial_k(const float* __restrict__ prob,
                               const float* __restrict__ hln,
                               float* __restrict__ part)
{
    int j = blockIdx.x * 256 + threadIdx.x;
    int c = blockIdx.y;
    float acc = 0.f;
    for (int t = c * 128; t < (c + 1) * 128; ++t)
        acc = fmaf(prob[t], hln[((size_t)t << 9) + j], acc);
    part[c * 512 + j] = acc;
}

__global__ void pool_reduce_k(const float* __restrict__ part,
                              float* __restrict__ hp)
{
    int j = blockIdx.x * 256 + threadIdx.x;
    float acc = 0.f;
    for (int c = 0; c < 32; ++c) acc += part[c * 512 + j];
    hp[j] = acc;
}

__global__ __launch_bounds__(256) void final_head_k(
    const float* __restrict__ hp, const float* __restrict__ cls_w,
    const float* __restrict__ cls_b, const int* __restrict__ label,
    float* __restrict__ out)
{
    const int w = threadIdx.x >> 6, lane = threadIdx.x & 63;
    float acc = 0.f;
    for (int k = lane; k < 512; k += 64) acc += hp[k] * cls_w[w * 512 + k];
#pragma unroll
    for (int o = 32; o; o >>= 1) acc += __shfl_down(acc, o, 64);
    __shared__ float lg[4];
    if (lane == 0) lg[w] = acc + cls_b[w];
    __syncthreads();
    if (threadIdx.x == 0) {
        float lce[4];
        for (int c = 0; c < 4; ++c) {
            float z = lg[c];
            float hz = 1.f / (1.f + expf(-z));
            float pc = fminf(fmaxf(hz, 1e-6f), 1.f - 1e-6f);
            lce[c] = logf(pc) - log1pf(-pc);
        }
        float mx = fmaxf(fmaxf(lce[0], lce[1]), fmaxf(lce[2], lce[3]));
        float se = 0.f;
        for (int c = 0; c < 4; ++c) se += expf(lce[c] - mx);
        for (int c = 0; c < 4; ++c) out[c] = lce[c];
        for (int c = 0; c < 4; ++c) out[4 + c] = expf(lce[c] - mx) / se;
        int lb = label[0];
        out[8] = -(lce[lb] - mx - logf(se));
    }
}

// ---------------------------------------------------------------------------
extern "C" void kernel_launch(void* const* d_in, const int* in_sizes, int n_in,
                              void* d_out, int out_size, void* d_ws, size_t ws_size,
                              hipStream_t stream)
{
    const float* data_s   = (const float*)d_in[0];
    const float* data_l   = (const float*)d_in[1];
    const int*   label    = (const int*)d_in[3];
    const float* fc1_w    = (const float*)d_in[4];
    const float* fc1_b    = (const float*)d_in[5];
    const float* ln_w     = (const float*)d_in[6];
    const float* ln_b     = (const float*)d_in[7];
    const float* in_proj_w= (const float*)d_in[8];
    const float* conv_w   = (const float*)d_in[9];
    const float* conv_b   = (const float*)d_in[10];
    const float* x_proj_w = (const float*)d_in[11];
    const float* dt_proj_w= (const float*)d_in[12];
    const float* dt_proj_b= (const float*)d_in[13];
    const float* A_log    = (const float*)d_in[14];
    const float* D_param  = (const float*)d_in[15];
    const float* out_proj_w=(const float*)d_in[16];
    const float* norm_w   = (const float*)d_in[17];
    const float* norm_b   = (const float*)d_in[18];
    const float* attn_w1  = (const float*)d_in[19];
    const float* attn_b1  = (const float*)d_in[20];
    const float* attn_w2  = (const float*)d_in[21];
    const float* attn_b2  = (const float*)d_in[22];
    const float* cls_w    = (const float*)d_in[23];
    const float* cls_b    = (const float*)d_in[24];
    float* out = (float*)d_out;

    // ---- f32 workspace ----
    float* ws = (float*)d_ws;
    size_t off = 0;
    float* h    = ws + off; off += (size_t)L_SEQ * DMODEL;      // 2M
    float* hn   = ws + off; off += (size_t)L_SEQ * DMODEL;      // 2M
    float* xdbl = ws + off; off += (size_t)L_SEQ * 64;          // 256K
    float* At   = ws + off; off += (size_t)L_SEQ * 128;         // 512K
    float* sc   = ws + off; off += L_SEQ;
    float* pb   = ws + off; off += L_SEQ;
    float* part = ws + off; off += 32 * 512;
    float* hp   = ws + off; off += 512;

    // ---- bf16 workspace ----
    __bf16* bws = (__bf16*)(ws + off);
    size_t boff = 0;
    __bf16* Acatb = bws + boff; boff += (size_t)L_SEQ * DIN;       // 4M
    __bf16* hnb   = bws + boff; boff += (size_t)L_SEQ * DMODEL;    // 2M
    __bf16* XZb   = bws + boff; boff += (size_t)L_SEQ * 2 * DI;    // 8M
    __bf16* XCb   = bws + boff; boff += (size_t)L_SEQ * DI;        // 4M
    __bf16* dtbB  = bws + boff; boff += (size_t)L_SEQ * DI;        // 4M
    __bf16* yzb   = bws + boff; boff += (size_t)L_SEQ * DI;        // 4M
    __bf16* sPb   = bws + boff; boff += (size_t)NCHK * DI * DS;    // 4M
    __bf16* sHb   = bws + boff; boff += (size_t)NCHK * DI * DS;    // 4M
    __bf16* HinB  = bws + boff; boff += (size_t)NCHK * DI * DS;    // 4M
    __bf16* wfc1b = bws + boff; boff += (size_t)DMODEL * DIN;
    __bf16* winb  = bws + boff; boff += (size_t)2 * 2 * DI * DMODEL;
    __bf16* wxpb  = bws + boff; boff += (size_t)2 * 64 * DI;
    __bf16* woutb = bws + boff; boff += (size_t)2 * DMODEL * DI;
    if (ws_size < off * sizeof(float) + boff * sizeof(__bf16)) return;

    // ---- weight conversions, one launch ----
    const int n0 = DMODEL * DIN / 8;            // fc1
    const int n1 = 2 * 2 * DI * DMODEL / 8;     // in_proj
    const int n2 = 2 * 64 * DI / 8;             // x_proj
    const int n3 = 2 * DMODEL * DI / 8;         // out_proj
    f2b4_k<<<(n0 + n1 + n2 + n3 + 255) / 256, 256, 0, stream>>>(
        fc1_w, wfc1b, n0, in_proj_w, winb, n1, x_proj_w, wxpb, n2, out_proj_w, woutb, n3);

    // h = relu(concat @ fc1_w.T + b)
    concat_bf_k<<<L_SEQ * DIN / 8 / 256, 256, 0, stream>>>(data_s, data_l, Acatb);
    gemm_mfma<64, 1, true, false, false><<<dim3(DMODEL / 64, L_SEQ / 128), 256, 0, stream>>>(
        Acatb, DIN, wfc1b, DIN, fc1_b, h, nullptr, DMODEL, DIN);

    for (int i = 0; i < 2; ++i) {
        const __bf16* inw = winb + (size_t)i * 2 * DI * DMODEL;
        const float* cwi = conv_w + (size_t)i * DI * DC;
        const float* cbi = conv_b + (size_t)i * DI;
        const __bf16* xpw = wxpb + (size_t)i * 64 * DI;
        const float* dtw = dt_proj_w + (size_t)i * DI * DTR;
        const float* dtbv= dt_proj_b + (size_t)i * DI;
        const float* Alg = A_log + (size_t)i * DI * DS;
        const float* Dpi = D_param + (size_t)i * DI;
        const __bf16* owi = woutb + (size_t)i * DMODEL * DI;

        layernorm_k<true><<<L_SEQ, 128, 0, stream>>>(h, ln_w + i * DMODEL, ln_b + i * DMODEL, nullptr, hnb);
        // XZ = hn @ inw.T  (N=2048 fused x|z, bf16 out)
        gemm_mfma<128, 0, false, false, true><<<dim3(2 * DI / 128, L_SEQ / 128), 256, 0, stream>>>(
            hnb, DMODEL, inw, DMODEL, nullptr, nullptr, XZb, 2 * DI, DMODEL);
        conv_silu_k<<<L_SEQ * DI / 4 / 256, 256, 0, stream>>>(XZb, cwi, cbi, XCb);
        // xdbl = XC @ xpw.T (N=64, f32 out)
        gemm_mfma<64, 0, false, false, false><<<dim3(1, L_SEQ / 128), 256, 0, stream>>>(
            XCb, DI, xpw, DI, nullptr, xdbl, nullptr, 64, DI);
        // dt = softplus(xdbl[:, :32] @ dtw.T + dtb) -> bf16
        gemm_bt<3, true, true><<<dim3(DI / 64, L_SEQ / 64), 256, 0, stream>>>(
            xdbl, 64, dtw, dtbv, nullptr, dtbB, DI, DTR);
        // selective scan (chunked, CL=16)
        scanA_k<<<dim3(DI / 256, NCHK), 256, 0, stream>>>(dtbB, XCb, xdbl, Alg, sPb, sHb);
        scanB_k<<<DI * DS / 64, 64, 0, stream>>>(sPb, sHb, HinB);
        scanC_k<<<dim3(DI / 256, NCHK), 256, 0, stream>>>(dtbB, XCb, xdbl, Alg, Dpi, XZb, HinB, yzb);
        // h += yz @ owi.T
        gemm_mfma<64, 0, false, true, false><<<dim3(DMODEL / 64, L_SEQ / 128), 256, 0, stream>>>(
            yzb, DI, owi, DI, nullptr, h, nullptr, DMODEL, DI);
    }

    // final LN (f32), attention pooling, head
    layernorm_k<false><<<L_SEQ, 128, 0, stream>>>(h, norm_w, norm_b, hn, nullptr);
    gemm_bt<2, true, false><<<dim3(128 / 64, L_SEQ / 64), 256, 0, stream>>>(
        hn, DMODEL, attn_w1, attn_b1, At, nullptr, 128, DMODEL);
    score_k<<<L_SEQ / 256, 256, 0, stream>>>(At, attn_w2, attn_b2, sc);
    softmax_k<<<1, 256, 0, stream>>>(sc, pb);
    pool_partial_k<<<dim3(2, 32), 256, 0, stream>>>(pb, hn, part);
    pool_reduce_k<<<2, 256, 0, stream>>>(part, hp);
    final_head_k<<<1, 256, 0, stream>>>(hp, cls_w, cls_b, label, out);
}